// Round 1
// baseline (28090.488 us; speedup 1.0000x reference)
//
#include <hip/hip_runtime.h>
#include <hip/hip_cooperative_groups.h>
#include <math.h>

namespace cg = cooperative_groups;

#define HID    1024
#define G4     4096      // 4*HID gate rows per layer
#define VOC    32000
#define SEQL   64
#define BOSTOK 1
#define NBLK   256
#define NTHR   1024
#define NWAVES (NTHR / 64)
#define TOTW   (NBLK * NWAVES)   // 4096 waves

struct P {
  const int*   src;
  const float* embE; const float* eWih; const float* eWhh; const float* ebih; const float* ebhh;
  const float* embD; const float* dWih; const float* dWhh; const float* dbih; const float* dbhh;
  const float* oW;   const float* ob;
  float* out;   // [64][32000] raw logits then log-probs
  float* ws;
};

__device__ __forceinline__ float wsum(float v) {
#pragma unroll
  for (int o = 32; o > 0; o >>= 1) v += __shfl_xor(v, o, 64);
  return v;
}

// partial (unreduced) 1024-dot: global row w . LDS vector v
__device__ __forceinline__ float dotg(const float* __restrict__ w, const float* v, int lane) {
  const float4* w4 = (const float4*)w;
  const float4* v4 = (const float4*)v;
  float acc = 0.f;
#pragma unroll
  for (int j = 0; j < 4; ++j) {
    float4 a = w4[lane + 64 * j];
    float4 b = v4[lane + 64 * j];
    acc += a.x * b.x + a.y * b.y + a.z * b.z + a.w * b.w;
  }
  return acc;
}

// LSTM elementwise: gates preact (4096, order i,f,g,o) + c_in -> h (LDS), optional c_out (global)
__device__ __forceinline__ void derive(const float* __restrict__ pa, const float* __restrict__ cin,
                                       float* __restrict__ cout, float* __restrict__ hout, int tid) {
  float gi = pa[tid], gf = pa[HID + tid], gg = pa[2 * HID + tid], go = pa[3 * HID + tid];
  float c  = cin ? cin[tid] : 0.f;
  float si = 1.f / (1.f + expf(-gi));
  float sf = 1.f / (1.f + expf(-gf));
  float so = 1.f / (1.f + expf(-go));
  float cn = sf * c + si * tanhf(gg);
  hout[tid] = so * tanhf(cn);
  if (cout) cout[tid] = cn;
}

__global__ void __launch_bounds__(NTHR) rnn_all(P p) {
  cg::grid_group grid = cg::this_grid();
  const int  tid  = threadIdx.x;
  const int  lane = tid & 63;
  const int  wv   = tid >> 6;
  const int  gw   = blockIdx.x * NWAVES + wv;
  const bool b0   = (blockIdx.x == 0);

  __shared__ __align__(16) float sx[HID];
  __shared__ __align__(16) float sh0[HID];
  __shared__ __align__(16) float sh1[HID];
  __shared__ float rv[NWAVES];
  __shared__ int   ri[NWAVES];
  __shared__ int   stok;

  // ---- workspace layout (ring buffers; d_ws is poisoned 0xAA, never read-before-write) ----
  float* pa0e = p.ws;              // 4 * G4
  float* pa1e = pa0e + 4 * G4;
  float* pa0d = pa1e + 4 * G4;
  float* pa1d = pa0d + 4 * G4;
  float* c0e  = pa1d + 4 * G4;     // 4 * HID each; slot s&3 = c entering step s
  float* c1e  = c0e + 4 * HID;
  float* c0d  = c1e + 4 * HID;
  float* c1d  = c0d + 4 * HID;
  float* B0   = c1d + 4 * HID;     // G4: Whh0d@h0 + biases for current dec step
  float* B1   = B0 + G4;           // G4
  float* pmv  = B1 + G4;           // NBLK per-block argmax partial values
  int*   pmi  = (int*)(pmv + NBLK);
  float* lsep = (float*)(pmi + NBLK); // 64 rows * 4 segs * 2 (m, s)

  const float* eW0i = p.eWih;  const float* eW1i = p.eWih + (size_t)G4 * HID;
  const float* eW0h = p.eWhh;  const float* eW1h = p.eWhh + (size_t)G4 * HID;
  const float* eb0i = p.ebih;  const float* eb1i = p.ebih + G4;
  const float* eb0h = p.ebhh;  const float* eb1h = p.ebhh + G4;
  const float* dW0i = p.dWih;  const float* dW1i = p.dWih + (size_t)G4 * HID;
  const float* dW0h = p.dWhh;  const float* dW1h = p.dWhh + (size_t)G4 * HID;
  const float* db0i = p.dbih;  const float* db1i = p.dbih + G4;
  const float* db0h = p.dbhh;  const float* db1h = p.dbhh + G4;

  // ================= encoder: skewed pipeline, phase k computes preact0(k) & preact1(k-1) =====
  for (int k = 0; k <= SEQL; ++k) {
    if (k < SEQL) {
      int tok = p.src[k];
      sx[tid] = p.embE[(size_t)tok * HID + tid];
    }
    if (k >= 1) {   // derive h0(k-1) from preact0(k-1); c entering step k-1
      derive(pa0e + ((k - 1) & 3) * G4,
             (k >= 2) ? (c0e + ((k - 1) & 3) * HID) : nullptr,
             b0 ? (c0e + (k & 3) * HID) : nullptr, sh0, tid);
    } else sh0[tid] = 0.f;
    if (k >= 2) {   // derive h1(k-2)
      derive(pa1e + ((k - 2) & 3) * G4,
             (k >= 3) ? (c1e + ((k - 2) & 3) * HID) : nullptr,
             b0 ? (c1e + ((k - 1) & 3) * HID) : nullptr, sh1, tid);
    } else sh1[tid] = 0.f;
    __syncthreads();

    for (int it = gw; it < 2 * G4; it += TOTW) {
      if (it < G4) {
        if (k < SEQL) {
          int r = it;
          float a = dotg(eW0i + (size_t)r * HID, sx, lane) +
                    dotg(eW0h + (size_t)r * HID, sh0, lane);
          float v = wsum(a) + eb0i[r] + eb0h[r];
          if (lane == 0) pa0e[(k & 3) * G4 + r] = v;
        }
      } else if (k >= 1) {
        int r = it - G4;
        float a = dotg(eW1i + (size_t)r * HID, sh0, lane) +
                  dotg(eW1h + (size_t)r * HID, sh1, lane);
        float v = wsum(a) + eb1i[r] + eb1h[r];
        if (lane == 0) pa1e[((k - 1) & 3) * G4 + r] = v;
      }
    }
    __threadfence();
    grid.sync();
  }

  // ================= decoder init: B0/B1 for step 0 from encoder final state ==================
  {
    derive(pa0e + (63 & 3) * G4, c0e + (63 & 3) * HID, b0 ? (c0d + 0) : nullptr, sh0, tid);
    derive(pa1e + (63 & 3) * G4, c1e + (63 & 3) * HID, b0 ? (c1d + 0) : nullptr, sh1, tid);
    __syncthreads();
    for (int it = gw; it < 2 * G4; it += TOTW) {
      if (it < G4) {
        int r = it;
        float v = wsum(dotg(dW0h + (size_t)r * HID, sh0, lane)) + db0i[r] + db0h[r];
        if (lane == 0) B0[r] = v;
      } else {
        int r = it - G4;
        float v = wsum(dotg(dW1h + (size_t)r * HID, sh1, lane)) + db1i[r] + db1h[r];
        if (lane == 0) B1[r] = v;
      }
    }
    __threadfence();
    grid.sync();
  }

  // ================= decoder: 3 phases per step ===============================================
  for (int t = 0; t < SEQL; ++t) {
    // ---- Ph1: token select (redundant per block) + preact0(t) = Wih0d@x + B0 ----
    if (t == 0) {
      if (tid == 0) stok = BOSTOK;
    } else if (wv == 0) {
      float bv = -1e30f; int bi = 0;
#pragma unroll
      for (int j = 0; j < NBLK / 64; ++j) {
        int   idx = lane + 64 * j;
        float v   = pmv[idx];
        int   i2  = pmi[idx];
        if (v > bv || (v == bv && i2 < bi)) { bv = v; bi = i2; }
      }
#pragma unroll
      for (int o = 32; o > 0; o >>= 1) {
        float v  = __shfl_xor(bv, o, 64);
        int   i2 = __shfl_xor(bi, o, 64);
        if (v > bv || (v == bv && i2 < bi)) { bv = v; bi = i2; }
      }
      if (lane == 0) stok = bi;
    }
    __syncthreads();
    sx[tid] = p.embD[(size_t)stok * HID + tid];
    __syncthreads();
    for (int it = gw; it < G4; it += TOTW) {
      float v = wsum(dotg(dW0i + (size_t)it * HID, sx, lane)) + B0[it];
      if (lane == 0) pa0d[(t & 3) * G4 + it] = v;
    }
    __threadfence();
    grid.sync();

    // ---- Ph2: h0d(t); preact1(t) = Wih1d@h0 + B1 ----
    derive(pa0d + (t & 3) * G4, c0d + (t & 3) * HID,
           b0 ? (c0d + ((t + 1) & 3) * HID) : nullptr, sh0, tid);
    __syncthreads();
    for (int it = gw; it < G4; it += TOTW) {
      float v = wsum(dotg(dW1i + (size_t)it * HID, sh0, lane)) + B1[it];
      if (lane == 0) pa1d[(t & 3) * G4 + it] = v;
    }
    __threadfence();
    grid.sync();

    // ---- Ph3: h1d(t); logits = outW@h1 + b (+argmax partials); B0/B1 for step t+1 ----
    derive(pa1d + (t & 3) * G4, c1d + (t & 3) * HID,
           b0 ? (c1d + ((t + 1) & 3) * HID) : nullptr, sh1, tid);
    __syncthreads();
    float bv = -1e30f; int bi = 0;
    for (int it = gw; it < VOC + 2 * G4; it += TOTW) {
      if (it < VOC) {
        float v = wsum(dotg(p.oW + (size_t)it * HID, sh1, lane)) + p.ob[it];
        if (lane == 0) p.out[(size_t)t * VOC + it] = v;
        if (v > bv) { bv = v; bi = it; }   // rows increase per wave -> first-max tie-break
      } else if (it < VOC + G4) {
        int r = it - VOC;
        float v = wsum(dotg(dW0h + (size_t)r * HID, sh0, lane)) + db0i[r] + db0h[r];
        if (lane == 0) B0[r] = v;
      } else {
        int r = it - VOC - G4;
        float v = wsum(dotg(dW1h + (size_t)r * HID, sh1, lane)) + db1i[r] + db1h[r];
        if (lane == 0) B1[r] = v;
      }
    }
    if (lane == 0) { rv[wv] = bv; ri[wv] = bi; }
    __syncthreads();
    if (tid == 0) {
      float v = rv[0]; int i2 = ri[0];
      for (int j = 1; j < NWAVES; ++j)
        if (rv[j] > v || (rv[j] == v && ri[j] < i2)) { v = rv[j]; i2 = ri[j]; }
      pmv[blockIdx.x] = v; pmi[blockIdx.x] = i2;
    }
    __threadfence();
    grid.sync();
  }

  // ================= epilogue: log_softmax over each of 64 rows (4 blocks per row) ============
  {
    const int row = blockIdx.x >> 2;
    const int seg = blockIdx.x & 3;
    float* base = p.out + (size_t)row * VOC + (size_t)seg * 8000;

    float lm = -1e30f;
    for (int i = tid; i < 8000; i += NTHR) lm = fmaxf(lm, base[i]);
#pragma unroll
    for (int o = 32; o > 0; o >>= 1) lm = fmaxf(lm, __shfl_xor(lm, o, 64));
    if (lane == 0) rv[wv] = lm;
    __syncthreads();
    float bm = rv[0];
#pragma unroll
    for (int j = 1; j < NWAVES; ++j) bm = fmaxf(bm, rv[j]);
    float ls = 0.f;
    for (int i = tid; i < 8000; i += NTHR) ls += expf(base[i] - bm);
    ls = wsum(ls);
    __syncthreads();
    if (lane == 0) rv[wv] = ls;
    __syncthreads();
    if (tid == 0) {
      float ss = 0.f;
      for (int j = 0; j < NWAVES; ++j) ss += rv[j];
      lsep[blockIdx.x * 2]     = bm;
      lsep[blockIdx.x * 2 + 1] = ss;
    }
    __threadfence();
    grid.sync();

    const float* lp = lsep + (size_t)row * 8;
    float M = fmaxf(fmaxf(lp[0], lp[2]), fmaxf(lp[4], lp[6]));
    float S = lp[1] * expf(lp[0] - M) + lp[3] * expf(lp[2] - M) +
              lp[5] * expf(lp[4] - M) + lp[7] * expf(lp[6] - M);
    float L = M + logf(S);
    for (int i = tid; i < 8000; i += NTHR) base[i] -= L;
  }
}

extern "C" void kernel_launch(void* const* d_in, const int* in_sizes, int n_in,
                              void* d_out, int out_size, void* d_ws, size_t ws_size,
                              hipStream_t stream) {
  P p;
  p.src  = (const int*)d_in[0];
  // d_in[1] = tgt (only its length matters; == SEQL)
  p.embE = (const float*)d_in[2];
  p.eWih = (const float*)d_in[3];
  p.eWhh = (const float*)d_in[4];
  p.ebih = (const float*)d_in[5];
  p.ebhh = (const float*)d_in[6];
  p.embD = (const float*)d_in[7];
  p.dWih = (const float*)d_in[8];
  p.dWhh = (const float*)d_in[9];
  p.dbih = (const float*)d_in[10];
  p.dbhh = (const float*)d_in[11];
  p.oW   = (const float*)d_in[12];
  p.ob   = (const float*)d_in[13];
  p.out  = (float*)d_out;
  p.ws   = (float*)d_ws;
  void* args[] = { &p };
  hipLaunchCooperativeKernel((const void*)rnn_all, dim3(NBLK), dim3(NTHR), args, 0, stream);
}

// Round 2
// 7950.252 us; speedup vs baseline: 3.5333x; 3.5333x over previous
//
#include <hip/hip_runtime.h>
#include <math.h>

#define HID    1024
#define G4     4096      // 4*HID gate rows per layer
#define VOC    32000
#define SEQL   64
#define BOSTOK 1
#define NBLK   256
#define NTHR   1024
#define NWAVES (NTHR / 64)
#define TOTW   (NBLK * NWAVES)   // 4096 waves

struct P {
  const int*   src;
  const float* embE; const float* eWih; const float* eWhh; const float* ebih; const float* ebhh;
  const float* embD; const float* dWih; const float* dWhh; const float* dbih; const float* dbhh;
  const float* oW;   const float* ob;
  float* out;   // [64][32000] raw logits then log-probs
  float* ws;
};

// ---- device-coherent (agent-scope, relaxed) data movement: no cache-maintenance instrs ----
__device__ __forceinline__ float gld(const float* p) {
  return __hip_atomic_load((float*)p, __ATOMIC_RELAXED, __HIP_MEMORY_SCOPE_AGENT);
}
__device__ __forceinline__ void gst(float* p, float v) {
  __hip_atomic_store(p, v, __ATOMIC_RELAXED, __HIP_MEMORY_SCOPE_AGENT);
}
__device__ __forceinline__ int gldi(const int* p) {
  return __hip_atomic_load((int*)p, __ATOMIC_RELAXED, __HIP_MEMORY_SCOPE_AGENT);
}
__device__ __forceinline__ void gsti(int* p, int v) {
  __hip_atomic_store(p, v, __ATOMIC_RELAXED, __HIP_MEMORY_SCOPE_AGENT);
}

// ---- lean grid barrier: leader-only atomics on (cnt, gen); no buffer_wbl2/inv storms ----
__device__ __forceinline__ void gridbar(unsigned* cnt, unsigned* gen) {
  __syncthreads();
  if (threadIdx.x == 0) {
    __builtin_amdgcn_s_waitcnt(0);   // all prior vmem (incl. relaxed atomic stores) complete
    unsigned g = __hip_atomic_load(gen, __ATOMIC_RELAXED, __HIP_MEMORY_SCOPE_AGENT);
    unsigned a = __hip_atomic_fetch_add(cnt, 1u, __ATOMIC_ACQ_REL, __HIP_MEMORY_SCOPE_AGENT);
    if (a == NBLK - 1) {
      __hip_atomic_store(cnt, 0u, __ATOMIC_RELAXED, __HIP_MEMORY_SCOPE_AGENT);
      __hip_atomic_fetch_add(gen, 1u, __ATOMIC_RELEASE, __HIP_MEMORY_SCOPE_AGENT);
    } else {
      while (__hip_atomic_load(gen, __ATOMIC_RELAXED, __HIP_MEMORY_SCOPE_AGENT) == g)
        __builtin_amdgcn_s_sleep(8);
      (void)__hip_atomic_load(gen, __ATOMIC_ACQUIRE, __HIP_MEMORY_SCOPE_AGENT);
    }
  }
  __syncthreads();
}

__device__ __forceinline__ float wsum(float v) {
#pragma unroll
  for (int o = 32; o > 0; o >>= 1) v += __shfl_xor(v, o, 64);
  return v;
}

// partial (unreduced) 1024-dot: global row w . LDS vector v
__device__ __forceinline__ float dotg(const float* __restrict__ w, const float* v, int lane) {
  const float4* w4 = (const float4*)w;
  const float4* v4 = (const float4*)v;
  float acc = 0.f;
#pragma unroll
  for (int j = 0; j < 4; ++j) {
    float4 a = w4[lane + 64 * j];
    float4 b = v4[lane + 64 * j];
    acc += a.x * b.x + a.y * b.y + a.z * b.z + a.w * b.w;
  }
  return acc;
}

// LSTM elementwise: gates preact (4096, order i,f,g,o) + c_in -> h (LDS), optional c_out (global)
__device__ __forceinline__ void derive(const float* __restrict__ pa, const float* __restrict__ cin,
                                       float* __restrict__ cout, float* __restrict__ hout, int tid) {
  float gi = gld(pa + tid), gf = gld(pa + HID + tid);
  float gg = gld(pa + 2 * HID + tid), go = gld(pa + 3 * HID + tid);
  float c  = cin ? gld(cin + tid) : 0.f;
  float si = 1.f / (1.f + expf(-gi));
  float sf = 1.f / (1.f + expf(-gf));
  float so = 1.f / (1.f + expf(-go));
  float cn = sf * c + si * tanhf(gg);
  hout[tid] = so * tanhf(cn);
  if (cout) gst(cout + tid, cn);
}

__global__ void init_bar(unsigned* bar) { bar[0] = 0; bar[1] = 0; }

__global__ void __launch_bounds__(NTHR) rnn_all(P p) {
  const int  tid  = threadIdx.x;
  const int  lane = tid & 63;
  const int  wv   = tid >> 6;
  const int  gw   = blockIdx.x * NWAVES + wv;
  const bool b0   = (blockIdx.x == 0);

  unsigned* cnt = (unsigned*)p.ws;
  unsigned* gen = cnt + 1;

  __shared__ __align__(16) float sx[HID];
  __shared__ __align__(16) float sh0[HID];
  __shared__ __align__(16) float sh1[HID];
  __shared__ float rv[NWAVES];
  __shared__ int   ri[NWAVES];
  __shared__ int   stok;

  // ---- workspace layout (ring buffers; barrier words occupy ws[0..63]) ----
  float* pa0e = p.ws + 64;         // 4 * G4
  float* pa1e = pa0e + 4 * G4;
  float* pa0d = pa1e + 4 * G4;
  float* pa1d = pa0d + 4 * G4;
  float* c0e  = pa1d + 4 * G4;     // 4 * HID each; slot s&3 = c entering step s
  float* c1e  = c0e + 4 * HID;
  float* c0d  = c1e + 4 * HID;
  float* c1d  = c0d + 4 * HID;
  float* B0   = c1d + 4 * HID;     // G4: Whh0d@h0 + biases for current dec step
  float* B1   = B0 + G4;           // G4
  float* pmv  = B1 + G4;           // NBLK per-block argmax partial values
  int*   pmi  = (int*)(pmv + NBLK);
  float* lsep = (float*)(pmi + NBLK); // 64 rows * 4 segs * 2 (m, s)

  const float* eW0i = p.eWih;  const float* eW1i = p.eWih + (size_t)G4 * HID;
  const float* eW0h = p.eWhh;  const float* eW1h = p.eWhh + (size_t)G4 * HID;
  const float* eb0i = p.ebih;  const float* eb1i = p.ebih + G4;
  const float* eb0h = p.ebhh;  const float* eb1h = p.ebhh + G4;
  const float* dW0i = p.dWih;  const float* dW1i = p.dWih + (size_t)G4 * HID;
  const float* dW0h = p.dWhh;  const float* dW1h = p.dWhh + (size_t)G4 * HID;
  const float* db0i = p.dbih;  const float* db1i = p.dbih + G4;
  const float* db0h = p.dbhh;  const float* db1h = p.dbhh + G4;

  // ================= encoder: skewed pipeline, phase k computes preact0(k) & preact1(k-1) =====
  for (int k = 0; k <= SEQL; ++k) {
    if (k < SEQL) {
      int tok = p.src[k];
      sx[tid] = p.embE[(size_t)tok * HID + tid];
    }
    if (k >= 1) {   // derive h0(k-1) from preact0(k-1); c entering step k-1
      derive(pa0e + ((k - 1) & 3) * G4,
             (k >= 2) ? (c0e + ((k - 1) & 3) * HID) : nullptr,
             b0 ? (c0e + (k & 3) * HID) : nullptr, sh0, tid);
    } else sh0[tid] = 0.f;
    if (k >= 2) {   // derive h1(k-2)
      derive(pa1e + ((k - 2) & 3) * G4,
             (k >= 3) ? (c1e + ((k - 2) & 3) * HID) : nullptr,
             b0 ? (c1e + ((k - 1) & 3) * HID) : nullptr, sh1, tid);
    } else sh1[tid] = 0.f;
    __syncthreads();

    for (int it = gw; it < 2 * G4; it += TOTW) {
      if (it < G4) {
        if (k < SEQL) {
          int r = it;
          float a = dotg(eW0i + (size_t)r * HID, sx, lane) +
                    dotg(eW0h + (size_t)r * HID, sh0, lane);
          float v = wsum(a) + eb0i[r] + eb0h[r];
          if (lane == 0) gst(pa0e + (k & 3) * G4 + r, v);
        }
      } else if (k >= 1) {
        int r = it - G4;
        float a = dotg(eW1i + (size_t)r * HID, sh0, lane) +
                  dotg(eW1h + (size_t)r * HID, sh1, lane);
        float v = wsum(a) + eb1i[r] + eb1h[r];
        if (lane == 0) gst(pa1e + ((k - 1) & 3) * G4 + r, v);
      }
    }
    gridbar(cnt, gen);
  }

  // ================= decoder init: B0/B1 for step 0 from encoder final state ==================
  {
    derive(pa0e + (63 & 3) * G4, c0e + (63 & 3) * HID, b0 ? (c0d + 0) : nullptr, sh0, tid);
    derive(pa1e + (63 & 3) * G4, c1e + (63 & 3) * HID, b0 ? (c1d + 0) : nullptr, sh1, tid);
    __syncthreads();
    for (int it = gw; it < 2 * G4; it += TOTW) {
      if (it < G4) {
        int r = it;
        float v = wsum(dotg(dW0h + (size_t)r * HID, sh0, lane)) + db0i[r] + db0h[r];
        if (lane == 0) gst(B0 + r, v);
      } else {
        int r = it - G4;
        float v = wsum(dotg(dW1h + (size_t)r * HID, sh1, lane)) + db1i[r] + db1h[r];
        if (lane == 0) gst(B1 + r, v);
      }
    }
    gridbar(cnt, gen);
  }

  // ================= decoder: 3 phases per step ===============================================
  for (int t = 0; t < SEQL; ++t) {
    // ---- Ph1: token select (redundant per block) + preact0(t) = Wih0d@x + B0 ----
    if (t == 0) {
      if (tid == 0) stok = BOSTOK;
    } else if (wv == 0) {
      float bv = -1e30f; int bi = 0;
#pragma unroll
      for (int j = 0; j < NBLK / 64; ++j) {
        int   idx = lane + 64 * j;
        float v   = gld(pmv + idx);
        int   i2  = gldi(pmi + idx);
        if (v > bv || (v == bv && i2 < bi)) { bv = v; bi = i2; }
      }
#pragma unroll
      for (int o = 32; o > 0; o >>= 1) {
        float v  = __shfl_xor(bv, o, 64);
        int   i2 = __shfl_xor(bi, o, 64);
        if (v > bv || (v == bv && i2 < bi)) { bv = v; bi = i2; }
      }
      if (lane == 0) stok = bi;
    }
    __syncthreads();
    sx[tid] = p.embD[(size_t)stok * HID + tid];
    __syncthreads();
    for (int it = gw; it < G4; it += TOTW) {
      float v = wsum(dotg(dW0i + (size_t)it * HID, sx, lane)) + gld(B0 + it);
      if (lane == 0) gst(pa0d + (t & 3) * G4 + it, v);
    }
    gridbar(cnt, gen);

    // ---- Ph2: h0d(t); preact1(t) = Wih1d@h0 + B1 ----
    derive(pa0d + (t & 3) * G4, c0d + (t & 3) * HID,
           b0 ? (c0d + ((t + 1) & 3) * HID) : nullptr, sh0, tid);
    __syncthreads();
    for (int it = gw; it < G4; it += TOTW) {
      float v = wsum(dotg(dW1i + (size_t)it * HID, sh0, lane)) + gld(B1 + it);
      if (lane == 0) gst(pa1d + (t & 3) * G4 + it, v);
    }
    gridbar(cnt, gen);

    // ---- Ph3: h1d(t); logits = outW@h1 + b (+argmax partials); B0/B1 for step t+1 ----
    derive(pa1d + (t & 3) * G4, c1d + (t & 3) * HID,
           b0 ? (c1d + ((t + 1) & 3) * HID) : nullptr, sh1, tid);
    __syncthreads();
    float bv = -1e30f; int bi = 0;
    for (int it = gw; it < VOC + 2 * G4; it += TOTW) {
      if (it < VOC) {
        float v = wsum(dotg(p.oW + (size_t)it * HID, sh1, lane)) + p.ob[it];
        if (lane == 0) gst(p.out + (size_t)t * VOC + it, v);
        if (v > bv) { bv = v; bi = it; }   // rows increase per wave -> first-max tie-break
      } else if (it < VOC + G4) {
        int r = it - VOC;
        float v = wsum(dotg(dW0h + (size_t)r * HID, sh0, lane)) + db0i[r] + db0h[r];
        if (lane == 0) gst(B0 + r, v);
      } else {
        int r = it - VOC - G4;
        float v = wsum(dotg(dW1h + (size_t)r * HID, sh1, lane)) + db1i[r] + db1h[r];
        if (lane == 0) gst(B1 + r, v);
      }
    }
    if (lane == 0) { rv[wv] = bv; ri[wv] = bi; }
    __syncthreads();
    if (tid == 0) {
      float v = rv[0]; int i2 = ri[0];
      for (int j = 1; j < NWAVES; ++j)
        if (rv[j] > v || (rv[j] == v && ri[j] < i2)) { v = rv[j]; i2 = ri[j]; }
      gst(pmv + blockIdx.x, v); gsti(pmi + blockIdx.x, i2);
    }
    gridbar(cnt, gen);
  }

  // ================= epilogue: log_softmax over each of 64 rows (4 blocks per row) ============
  {
    const int row = blockIdx.x >> 2;
    const int seg = blockIdx.x & 3;
    float* base = p.out + (size_t)row * VOC + (size_t)seg * 8000;

    float lm = -1e30f;
    for (int i = tid; i < 8000; i += NTHR) lm = fmaxf(lm, gld(base + i));
#pragma unroll
    for (int o = 32; o > 0; o >>= 1) lm = fmaxf(lm, __shfl_xor(lm, o, 64));
    if (lane == 0) rv[wv] = lm;
    __syncthreads();
    float bm = rv[0];
#pragma unroll
    for (int j = 1; j < NWAVES; ++j) bm = fmaxf(bm, rv[j]);
    float ls = 0.f;
    for (int i = tid; i < 8000; i += NTHR) ls += expf(gld(base + i) - bm);
    ls = wsum(ls);
    __syncthreads();
    if (lane == 0) rv[wv] = ls;
    __syncthreads();
    if (tid == 0) {
      float ss = 0.f;
      for (int j = 0; j < NWAVES; ++j) ss += rv[j];
      gst(lsep + blockIdx.x * 2,     bm);
      gst(lsep + blockIdx.x * 2 + 1, ss);
    }
    gridbar(cnt, gen);

    const float* lp = lsep + (size_t)row * 8;
    float l0 = gld(lp), l2 = gld(lp + 2), l4 = gld(lp + 4), l6 = gld(lp + 6);
    float s1 = gld(lp + 1), s3 = gld(lp + 3), s5 = gld(lp + 5), s7 = gld(lp + 7);
    float M = fmaxf(fmaxf(l0, l2), fmaxf(l4, l6));
    float S = s1 * expf(l0 - M) + s3 * expf(l2 - M) +
              s5 * expf(l4 - M) + s7 * expf(l6 - M);
    float L = M + logf(S);
    for (int i = tid; i < 8000; i += NTHR) base[i] = gld(base + i) - L;
  }
}

extern "C" void kernel_launch(void* const* d_in, const int* in_sizes, int n_in,
                              void* d_out, int out_size, void* d_ws, size_t ws_size,
                              hipStream_t stream) {
  P p;
  p.src  = (const int*)d_in[0];
  // d_in[1] = tgt (only its length matters; == SEQL)
  p.embE = (const float*)d_in[2];
  p.eWih = (const float*)d_in[3];
  p.eWhh = (const float*)d_in[4];
  p.ebih = (const float*)d_in[5];
  p.ebhh = (const float*)d_in[6];
  p.embD = (const float*)d_in[7];
  p.dWih = (const float*)d_in[8];
  p.dWhh = (const float*)d_in[9];
  p.dbih = (const float*)d_in[10];
  p.dbhh = (const float*)d_in[11];
  p.oW   = (const float*)d_in[12];
  p.ob   = (const float*)d_in[13];
  p.out  = (float*)d_out;
  p.ws   = (float*)d_ws;

  hipLaunchKernelGGL(init_bar, dim3(1), dim3(1), 0, stream, (unsigned*)d_ws);
  void* args[] = { &p };
  hipLaunchCooperativeKernel((const void*)rnn_all, dim3(NBLK), dim3(NTHR), args, 0, stream);
}